// Round 1
// baseline (384.900 us; speedup 1.0000x reference)
//
#include <hip/hip_runtime.h>
#include <math.h>

#define B 8
#define IMH 512
#define IMW 512
#define HW (IMH*IMW)
#define NBINS 256

// pyramid per-image: levels 1..4 (256^2, 128^2, 64^2, 32^2)
#define PYR_PER_IMG (65536 + 16384 + 4096 + 1024)   // 87040
#define PYR_OFF_L1 0
#define PYR_OFF_L2 65536
#define PYR_OFF_L3 81920
#define PYR_OFF_L4 86016

// workspace float-index offsets
#define OFF_PREDL 0
#define OFF_TGTL  (B*HW)
#define OFF_PPYR  (2*B*HW)
#define OFF_TPYR  (OFF_PPYR + B*PYR_PER_IMG)
#define OFF_HISTP (OFF_TPYR + B*PYR_PER_IMG)        // uint32 region
#define OFF_HISTT (OFF_HISTP + B*3*NBINS)
#define OFF_ACC   (OFF_HISTT + B*3*NBINS)           // doubles (byte off divisible by 8)
// doubles: ssim_acc[B*5], cs_acc[B*5], lab_sum[1]  -> 81 doubles

__device__ __forceinline__ float blockReduceSum(float v, float* smem4) {
    int lane = threadIdx.x & 63;
    int wid  = threadIdx.x >> 6;
    #pragma unroll
    for (int o = 32; o >= 1; o >>= 1) v += __shfl_down(v, o, 64);
    if (lane == 0) smem4[wid] = v;
    __syncthreads();
    if (wid == 0) {
        v = (lane < ((int)blockDim.x >> 6)) ? smem4[lane] : 0.0f;
        #pragma unroll
        for (int o = 2; o >= 1; o >>= 1) v += __shfl_down(v, o, 64);
    }
    __syncthreads();   // allow smem4 reuse by a subsequent call
    return v;          // valid in thread 0
}

__device__ __forceinline__ void rgb2lab(float r, float g, float b, float* out) {
    float v[3] = {r, g, b};
    float lin[3];
    #pragma unroll
    for (int c = 0; c < 3; ++c) {
        float x = v[c];
        lin[c] = (x <= 0.04045f) ? (x / 12.92f)
                                 : powf((fmaxf(x, 1e-4f) + 0.055f) / 1.055f, 2.4f);
    }
    float X = 0.412453f*lin[0] + 0.357580f*lin[1] + 0.180423f*lin[2];
    float Y = 0.212671f*lin[0] + 0.715160f*lin[1] + 0.072169f*lin[2];
    float Z = 0.019334f*lin[0] + 0.119193f*lin[1] + 0.950227f*lin[2];
    X *= (float)(1.0/0.950456);
    Z *= (float)(1.0/1.088754);
    const float eps3  = (float)((6.0/29.0)*(6.0/29.0)*(6.0/29.0));
    const float d3e2  = (float)(3.0*(6.0/29.0)*(6.0/29.0));
    const float c429  = (float)(4.0/29.0);
    float xyz[3] = {X, Y, Z};
    float f[3];
    #pragma unroll
    for (int c = 0; c < 3; ++c) {
        f[c] = (xyz[c] <= eps3) ? (xyz[c] / d3e2 + c429)
                                : powf(fmaxf(xyz[c], 1e-4f), 1.0f/3.0f);
    }
    float L = 116.0f*f[1] - 16.0f;
    float A = 500.0f*f[0] - 500.0f*f[1];
    float Bc = 200.0f*f[1] - 200.0f*f[2];
    out[0] = L / 100.0f;
    out[1] = (A / 110.0f + 1.0f) / 2.0f;
    out[2] = (Bc / 110.0f + 1.0f) / 2.0f;
}

__global__ void zero_kernel(unsigned* p, int n) {
    int i = blockIdx.x * 256 + threadIdx.x;
    if (i < n) p[i] = 0;
}

__global__ void lab_hist_kernel(const float* __restrict__ pred,
                                const float* __restrict__ tgt,
                                float* __restrict__ ws_f,
                                unsigned* __restrict__ histP,
                                unsigned* __restrict__ histT,
                                double* __restrict__ labSum) {
    __shared__ unsigned lhist[6 * NBINS];
    __shared__ float red4[4];
    int t = threadIdx.x;
    for (int i = t; i < 6 * NBINS; i += 256) lhist[i] = 0;
    __syncthreads();

    int b = blockIdx.y;
    int pix = blockIdx.x * 256 + t;
    const float* pi = pred + (size_t)b * 3 * HW + pix;
    const float* ti = tgt  + (size_t)b * 3 * HW + pix;

    float pl[3], tl[3];
    rgb2lab(pi[0], pi[HW], pi[2*HW], pl);
    rgb2lab(ti[0], ti[HW], ti[2*HW], tl);

    float l1 = 0.0f;
    #pragma unroll
    for (int c = 0; c < 3; ++c) {
        pl[c] = fminf(fmaxf(pl[c], 0.0f), 1.0f);
        tl[c] = fminf(fmaxf(tl[c], 0.0f), 1.0f);
        l1 += fabsf(pl[c] - tl[c]);
        int ip = (int)floorf(pl[c] * (float)NBINS);
        ip = min(max(ip, 0), NBINS - 1);
        int it = (int)floorf(tl[c] * (float)NBINS);
        it = min(max(it, 0), NBINS - 1);
        atomicAdd(&lhist[c * NBINS + ip], 1u);
        atomicAdd(&lhist[(3 + c) * NBINS + it], 1u);
    }

    // store clipped L channels for SSIM
    ws_f[OFF_PREDL + (size_t)b * HW + pix] = pl[0];
    ws_f[OFF_TGTL  + (size_t)b * HW + pix] = tl[0];

    __syncthreads();
    for (int i = t; i < 3 * NBINS; i += 256) {
        unsigned v = lhist[i];
        if (v) atomicAdd(&histP[b * 3 * NBINS + i], v);
        v = lhist[3 * NBINS + i];
        if (v) atomicAdd(&histT[b * 3 * NBINS + i], v);
    }

    float tot = blockReduceSum(l1, red4);
    if (t == 0) atomicAdd(labSum, (double)tot);
}

__global__ void pool_kernel(const float* __restrict__ srcP,
                            const float* __restrict__ srcT,
                            float* __restrict__ dstP,
                            float* __restrict__ dstT,
                            int srcStride, int dstStride, int dw) {
    int b = blockIdx.y;
    int p = blockIdx.x * 256 + threadIdx.x;
    int y = p / dw, x = p % dw;
    int sw = dw * 2;
    const float* s = srcP + (size_t)b * srcStride + (size_t)(2*y) * sw + 2*x;
    dstP[(size_t)b * dstStride + p] = 0.25f * (s[0] + s[1] + s[sw] + s[sw + 1]);
    s = srcT + (size_t)b * srcStride + (size_t)(2*y) * sw + 2*x;
    dstT[(size_t)b * dstStride + p] = 0.25f * (s[0] + s[1] + s[sw] + s[sw + 1]);
}

__global__ void ssim_kernel(const float* __restrict__ i1base,
                            const float* __restrict__ i2base,
                            int imgStride, int h, int w,
                            double* __restrict__ sAcc,
                            double* __restrict__ cAcc,
                            int level) {
    __shared__ float red4[4];
    int b = blockIdx.y;
    int p = blockIdx.x * 256 + threadIdx.x;
    int y = p / w, x = p % w;
    const float* i1 = i1base + (size_t)b * imgStride;
    const float* i2 = i2base + (size_t)b * imgStride;

    // Gaussian window (matches np: double normalize then f32 cast)
    double gd[5]; double gs = 0.0;
    #pragma unroll
    for (int i = 0; i < 5; ++i) { gd[i] = exp(-(double)((i-2)*(i-2)) / 4.5); gs += gd[i]; }
    #pragma unroll
    for (int i = 0; i < 5; ++i) gd[i] /= gs;

    float m1 = 0.f, m2 = 0.f, m11 = 0.f, m22 = 0.f, m12 = 0.f;
    #pragma unroll
    for (int dy = -2; dy <= 2; ++dy) {
        int yy = y + dy;
        if ((unsigned)yy >= (unsigned)h) continue;
        #pragma unroll
        for (int dx = -2; dx <= 2; ++dx) {
            int xx = x + dx;
            if ((unsigned)xx >= (unsigned)w) continue;
            float wgt = (float)(gd[dy+2] * gd[dx+2]);
            float a = i1[yy * w + xx];
            float c = i2[yy * w + xx];
            m1  += wgt * a;
            m2  += wgt * c;
            m11 += wgt * a * a;
            m22 += wgt * c * c;
            m12 += wgt * a * c;
        }
    }
    const float C1 = (float)(0.01 * 0.01);
    const float C2 = (float)(0.03 * 0.03);
    float s1  = m11 - m1 * m1;
    float s2  = m22 - m2 * m2;
    float s12 = m12 - m1 * m2;
    float den2 = s1 + s2 + C2;
    float ssimv = ((2.0f*m1*m2 + C1) * (2.0f*s12 + C2)) / ((m1*m1 + m2*m2 + C1) * den2);
    float csv   = (2.0f*s12 + C2) / den2;

    float ssum = blockReduceSum(ssimv, red4);
    float csum = blockReduceSum(csv, red4);
    if (threadIdx.x == 0) {
        atomicAdd(&sAcc[b * 5 + level], (double)ssum);
        atomicAdd(&cAcc[b * 5 + level], (double)csum);
    }
}

__global__ void final_kernel(const unsigned* __restrict__ histP,
                             const unsigned* __restrict__ histT,
                             const double* __restrict__ sAcc,
                             const double* __restrict__ cAcc,
                             const double* __restrict__ labSum,
                             float* __restrict__ out) {
    __shared__ float red4[4];
    __shared__ float l1s[B];
    int t = threadIdx.x;
    for (int b = 0; b < B; ++b) {
        float s = 0.0f;
        for (int i = t; i < 3 * NBINS; i += 256) {
            int d = (int)histP[b * 3 * NBINS + i] - (int)histT[b * 3 * NBINS + i];
            s += fabsf((float)d);
        }
        float tot = blockReduceSum(s, red4);
        if (t == 0) l1s[b] = tot;
        __syncthreads();
    }
    if (t == 0) {
        // histogram loss
        float hist_loss = 0.0f;
        for (int b = 0; b < B; ++b) {
            float l1 = l1s[b] / (float)(3 * NBINS);
            float wgt = exp2f((float)(b - B));   // 2^(b - n), n = B = 8
            hist_loss += wgt * (l1 + 1.0f);
        }
        float scaler = (float)HW / 20.0f;
        hist_loss = hist_loss / (float)B / scaler;
        float lab_l1 = (float)(labSum[0] / (double)((size_t)B * 3 * HW));
        out[0] = lab_l1 + hist_loss;

        // MS-SSIM
        const float msw[5] = {0.0448f, 0.2856f, 0.3001f, 0.2363f, 0.1333f};
        const int npix[5] = {HW, HW/4, HW/16, HW/64, HW/256};
        float loss = 0.0f;
        for (int b = 0; b < B; ++b) {
            float ms = 1.0f;
            for (int l = 0; l < 4; ++l) {
                float cs = (float)(cAcc[b * 5 + l] / (double)npix[l]);
                float csn = (cs + 1.0f) / 2.0f;
                ms *= powf(csn, msw[l]);
            }
            float sm = (float)(sAcc[b * 5 + 4] / (double)npix[4]);
            float smn = (sm + 1.0f) / 2.0f;
            ms *= powf(smn, msw[4]);
            loss += 1.0f - ms;
        }
        out[1] = loss / (float)B;
    }
}

extern "C" void kernel_launch(void* const* d_in, const int* in_sizes, int n_in,
                              void* d_out, int out_size, void* d_ws, size_t ws_size,
                              hipStream_t stream) {
    const float* pred = (const float*)d_in[1];
    const float* tgt  = (const float*)d_in[2];
    float* ws_f = (float*)d_ws;

    float* predL = ws_f + OFF_PREDL;
    float* tgtL  = ws_f + OFF_TGTL;
    float* ppyr  = ws_f + OFF_PPYR;
    float* tpyr  = ws_f + OFF_TPYR;
    unsigned* histP = (unsigned*)(ws_f + OFF_HISTP);
    unsigned* histT = (unsigned*)(ws_f + OFF_HISTT);
    double* accs  = (double*)(ws_f + OFF_ACC);
    double* sAcc  = accs;        // B*5
    double* cAcc  = accs + B*5;  // B*5
    double* labSum = accs + 2*B*5;
    float* out = (float*)d_out;

    // zero histograms + accumulators (ws is re-poisoned before every call)
    int zeroWords = 2 * B * 3 * NBINS + 81 * 2;
    zero_kernel<<<(zeroWords + 255)/256, 256, 0, stream>>>((unsigned*)(ws_f + OFF_HISTP), zeroWords);

    lab_hist_kernel<<<dim3(HW/256, B), 256, 0, stream>>>(pred, tgt, ws_f, histP, histT, labSum);

    // pyramid: level l from level l-1 (pred and tgt together)
    pool_kernel<<<dim3((256*256)/256, B), 256, 0, stream>>>(predL, tgtL,
        ppyr + PYR_OFF_L1, tpyr + PYR_OFF_L1, HW, PYR_PER_IMG, 256);
    pool_kernel<<<dim3((128*128)/256, B), 256, 0, stream>>>(ppyr + PYR_OFF_L1, tpyr + PYR_OFF_L1,
        ppyr + PYR_OFF_L2, tpyr + PYR_OFF_L2, PYR_PER_IMG, PYR_PER_IMG, 128);
    pool_kernel<<<dim3((64*64)/256, B), 256, 0, stream>>>(ppyr + PYR_OFF_L2, tpyr + PYR_OFF_L2,
        ppyr + PYR_OFF_L3, tpyr + PYR_OFF_L3, PYR_PER_IMG, PYR_PER_IMG, 64);
    pool_kernel<<<dim3((32*32)/256, B), 256, 0, stream>>>(ppyr + PYR_OFF_L3, tpyr + PYR_OFF_L3,
        ppyr + PYR_OFF_L4, tpyr + PYR_OFF_L4, PYR_PER_IMG, PYR_PER_IMG, 32);

    // SSIM per level
    ssim_kernel<<<dim3(HW/256, B), 256, 0, stream>>>(predL, tgtL, HW, IMH, IMW, sAcc, cAcc, 0);
    ssim_kernel<<<dim3((256*256)/256, B), 256, 0, stream>>>(ppyr + PYR_OFF_L1, tpyr + PYR_OFF_L1,
        PYR_PER_IMG, 256, 256, sAcc, cAcc, 1);
    ssim_kernel<<<dim3((128*128)/256, B), 256, 0, stream>>>(ppyr + PYR_OFF_L2, tpyr + PYR_OFF_L2,
        PYR_PER_IMG, 128, 128, sAcc, cAcc, 2);
    ssim_kernel<<<dim3((64*64)/256, B), 256, 0, stream>>>(ppyr + PYR_OFF_L3, tpyr + PYR_OFF_L3,
        PYR_PER_IMG, 64, 64, sAcc, cAcc, 3);
    ssim_kernel<<<dim3((32*32)/256, B), 256, 0, stream>>>(ppyr + PYR_OFF_L4, tpyr + PYR_OFF_L4,
        PYR_PER_IMG, 32, 32, sAcc, cAcc, 4);

    final_kernel<<<1, 256, 0, stream>>>(histP, histT, sAcc, cAcc, labSum, out);
}

// Round 2
// 264.692 us; speedup vs baseline: 1.4541x; 1.4541x over previous
//
#include <hip/hip_runtime.h>
#include <math.h>

#define B 8
#define IMH 512
#define IMW 512
#define HW (IMH*IMW)
#define NBINS 256

// pyramid per-image: levels 1..4 (256^2, 128^2, 64^2, 32^2)
#define PYR_PER_IMG (65536 + 16384 + 4096 + 1024)   // 87040
#define PYR_OFF_L1 0
#define PYR_OFF_L2 65536
#define PYR_OFF_L3 81920
#define PYR_OFF_L4 86016

// workspace float-index offsets
#define OFF_PREDL 0
#define OFF_TGTL  (B*HW)
#define OFF_PPYR  (2*B*HW)
#define OFF_TPYR  (OFF_PPYR + B*PYR_PER_IMG)
#define OFF_HISTP (OFF_TPYR + B*PYR_PER_IMG)        // uint32 region
#define OFF_HISTT (OFF_HISTP + B*3*NBINS)
#define OFF_ACC   (OFF_HISTT + B*3*NBINS)           // doubles (byte off divisible by 8)
// doubles: ssim_acc[B*5], cs_acc[B*5], lab_sum[1]  -> 81 doubles

__device__ __forceinline__ float blockReduceSum(float v, float* smem4) {
    int lane = threadIdx.x & 63;
    int wid  = threadIdx.x >> 6;
    #pragma unroll
    for (int o = 32; o >= 1; o >>= 1) v += __shfl_down(v, o, 64);
    if (lane == 0) smem4[wid] = v;
    __syncthreads();
    if (wid == 0) {
        v = (lane < ((int)blockDim.x >> 6)) ? smem4[lane] : 0.0f;
        #pragma unroll
        for (int o = 2; o >= 1; o >>= 1) v += __shfl_down(v, o, 64);
    }
    __syncthreads();   // allow smem4 reuse by a subsequent call
    return v;          // valid in thread 0
}

// native exp2/log2 (v_exp_f32 / v_log_f32, <=1 ulp). x must be > 0.
__device__ __forceinline__ float fastpow(float x, float y) {
    return __builtin_amdgcn_exp2f(y * __builtin_amdgcn_logf(x));
}

__device__ __forceinline__ void rgb2lab(float r, float g, float b, float* out) {
    float v[3] = {r, g, b};
    float lin[3];
    #pragma unroll
    for (int c = 0; c < 3; ++c) {
        float x = v[c];
        lin[c] = (x <= 0.04045f) ? (x * (float)(1.0/12.92))
                                 : fastpow((fmaxf(x, 1e-4f) + 0.055f) * (float)(1.0/1.055), 2.4f);
    }
    float X = 0.412453f*lin[0] + 0.357580f*lin[1] + 0.180423f*lin[2];
    float Y = 0.212671f*lin[0] + 0.715160f*lin[1] + 0.072169f*lin[2];
    float Z = 0.019334f*lin[0] + 0.119193f*lin[1] + 0.950227f*lin[2];
    X *= (float)(1.0/0.950456);
    Z *= (float)(1.0/1.088754);
    const float eps3   = (float)((6.0/29.0)*(6.0/29.0)*(6.0/29.0));
    const float rd3e2  = (float)(1.0/(3.0*(6.0/29.0)*(6.0/29.0)));
    const float c429   = (float)(4.0/29.0);
    float xyz[3] = {X, Y, Z};
    float f[3];
    #pragma unroll
    for (int c = 0; c < 3; ++c) {
        f[c] = (xyz[c] <= eps3) ? (xyz[c] * rd3e2 + c429)
                                : fastpow(fmaxf(xyz[c], 1e-4f), (float)(1.0/3.0));
    }
    float L = 116.0f*f[1] - 16.0f;
    float A = 500.0f*f[0] - 500.0f*f[1];
    float Bc = 200.0f*f[1] - 200.0f*f[2];
    out[0] = L * 0.01f;
    out[1] = (A * (float)(1.0/110.0) + 1.0f) * 0.5f;
    out[2] = (Bc * (float)(1.0/110.0) + 1.0f) * 0.5f;
}

__global__ void zero_kernel(unsigned* p, int n) {
    int i = blockIdx.x * 256 + threadIdx.x;
    if (i < n) p[i] = 0;
}

// 4 pixels per thread, float4 loads. grid (HW/1024, B) x 256
__global__ void lab_hist_kernel(const float* __restrict__ pred,
                                const float* __restrict__ tgt,
                                float* __restrict__ ws_f,
                                unsigned* __restrict__ histP,
                                unsigned* __restrict__ histT,
                                double* __restrict__ labSum) {
    __shared__ unsigned lhist[6 * NBINS];
    __shared__ float red4[4];
    int t = threadIdx.x;
    for (int i = t; i < 6 * NBINS; i += 256) lhist[i] = 0;
    __syncthreads();

    int b = blockIdx.y;
    int pix = (blockIdx.x * 256 + t) * 4;
    const float* pbase = pred + (size_t)b * 3 * HW + pix;
    const float* tbase = tgt  + (size_t)b * 3 * HW + pix;

    float4 pr = *(const float4*)(pbase);
    float4 pg = *(const float4*)(pbase + HW);
    float4 pb = *(const float4*)(pbase + 2*HW);
    float4 tr = *(const float4*)(tbase);
    float4 tg = *(const float4*)(tbase + HW);
    float4 tb = *(const float4*)(tbase + 2*HW);

    float prA[4] = {pr.x, pr.y, pr.z, pr.w};
    float pgA[4] = {pg.x, pg.y, pg.z, pg.w};
    float pbA[4] = {pb.x, pb.y, pb.z, pb.w};
    float trA[4] = {tr.x, tr.y, tr.z, tr.w};
    float tgA[4] = {tg.x, tg.y, tg.z, tg.w};
    float tbA[4] = {tb.x, tb.y, tb.z, tb.w};

    float l1 = 0.0f;
    float pls[4], tls[4];
    #pragma unroll
    for (int k = 0; k < 4; ++k) {
        float pl[3], tl[3];
        rgb2lab(prA[k], pgA[k], pbA[k], pl);
        rgb2lab(trA[k], tgA[k], tbA[k], tl);
        #pragma unroll
        for (int c = 0; c < 3; ++c) {
            pl[c] = fminf(fmaxf(pl[c], 0.0f), 1.0f);
            tl[c] = fminf(fmaxf(tl[c], 0.0f), 1.0f);
            l1 += fabsf(pl[c] - tl[c]);
            int ip = min(max((int)floorf(pl[c] * (float)NBINS), 0), NBINS - 1);
            int it = min(max((int)floorf(tl[c] * (float)NBINS), 0), NBINS - 1);
            atomicAdd(&lhist[c * NBINS + ip], 1u);
            atomicAdd(&lhist[(3 + c) * NBINS + it], 1u);
        }
        pls[k] = pl[0];
        tls[k] = tl[0];
    }

    // store clipped L channels for SSIM
    *(float4*)(ws_f + OFF_PREDL + (size_t)b * HW + pix) = make_float4(pls[0], pls[1], pls[2], pls[3]);
    *(float4*)(ws_f + OFF_TGTL  + (size_t)b * HW + pix) = make_float4(tls[0], tls[1], tls[2], tls[3]);

    __syncthreads();
    for (int i = t; i < 3 * NBINS; i += 256) {
        unsigned v = lhist[i];
        if (v) atomicAdd(&histP[b * 3 * NBINS + i], v);
        v = lhist[3 * NBINS + i];
        if (v) atomicAdd(&histT[b * 3 * NBINS + i], v);
    }

    float tot = blockReduceSum(l1, red4);
    if (t == 0) atomicAdd(labSum, (double)tot);
}

// one block = one 32x32 L0 tile -> produces L1 16x16, L2 8x8, L3 4x4, L4 2x2
// grid (256, B) x 256
__global__ void pyramid_kernel(const float* __restrict__ l0p,
                               const float* __restrict__ l0t,
                               float* __restrict__ ppyr,
                               float* __restrict__ tpyr) {
    __shared__ float s1[256];
    __shared__ float s2[64];
    __shared__ float s3[16];
    int b = blockIdx.y;
    int r = blockIdx.x;
    int ty0 = (r >> 4) << 5;
    int tx0 = (r & 15) << 5;
    int t = threadIdx.x;
    int ly = t >> 4, lx = t & 15;
    #pragma unroll
    for (int img = 0; img < 2; ++img) {
        const float* src = (img == 0 ? l0p : l0t) + (size_t)b * HW;
        float* dst = (img == 0 ? ppyr : tpyr) + (size_t)b * PYR_PER_IMG;
        int sy = ty0 + 2*ly, sx = tx0 + 2*lx;
        const float* s = src + sy * 512 + sx;
        float v1 = 0.25f * (s[0] + s[1] + s[512] + s[513]);
        dst[PYR_OFF_L1 + ((ty0 >> 1) + ly) * 256 + ((tx0 >> 1) + lx)] = v1;
        s1[t] = v1;
        __syncthreads();
        if (t < 64) {
            int y2 = t >> 3, x2 = t & 7;
            float v2 = 0.25f * (s1[(2*y2)*16 + 2*x2] + s1[(2*y2)*16 + 2*x2 + 1] +
                                s1[(2*y2+1)*16 + 2*x2] + s1[(2*y2+1)*16 + 2*x2 + 1]);
            dst[PYR_OFF_L2 + ((ty0 >> 2) + y2) * 128 + ((tx0 >> 2) + x2)] = v2;
            s2[t] = v2;
        }
        __syncthreads();
        if (t < 16) {
            int y3 = t >> 2, x3 = t & 3;
            float v3 = 0.25f * (s2[(2*y3)*8 + 2*x3] + s2[(2*y3)*8 + 2*x3 + 1] +
                                s2[(2*y3+1)*8 + 2*x3] + s2[(2*y3+1)*8 + 2*x3 + 1]);
            dst[PYR_OFF_L3 + ((ty0 >> 3) + y3) * 64 + ((tx0 >> 3) + x3)] = v3;
            s3[t] = v3;
        }
        __syncthreads();
        if (t < 4) {
            int y4 = t >> 1, x4 = t & 1;
            float v4 = 0.25f * (s3[(2*y4)*4 + 2*x4] + s3[(2*y4)*4 + 2*x4 + 1] +
                                s3[(2*y4+1)*4 + 2*x4] + s3[(2*y4+1)*4 + 2*x4 + 1]);
            dst[PYR_OFF_L4 + ((ty0 >> 4) + y4) * 32 + ((tx0 >> 4) + x4)] = v4;
        }
        __syncthreads();
    }
}

// all 5 levels fused: 1364 blocks per image (1024 L0, 256 L1, 64 L2, 16 L3, 4 L4)
__global__ void ssim_kernel(const float* __restrict__ predL,
                            const float* __restrict__ tgtL,
                            const float* __restrict__ ppyr,
                            const float* __restrict__ tpyr,
                            double* __restrict__ sAcc,
                            double* __restrict__ cAcc) {
    __shared__ float red4[4];
    int b = blockIdx.y;
    int bx = blockIdx.x;

    int lvl, pblk;
    if (bx < 1024)      { lvl = 0; pblk = bx; }
    else if (bx < 1280) { lvl = 1; pblk = bx - 1024; }
    else if (bx < 1344) { lvl = 2; pblk = bx - 1280; }
    else if (bx < 1360) { lvl = 3; pblk = bx - 1344; }
    else                { lvl = 4; pblk = bx - 1360; }

    const int offs[5] = {0, PYR_OFF_L1, PYR_OFF_L2, PYR_OFF_L3, PYR_OFF_L4};
    int w = 512 >> lvl;
    const float* i1;
    const float* i2;
    if (lvl == 0) {
        i1 = predL + (size_t)b * HW;
        i2 = tgtL  + (size_t)b * HW;
    } else {
        i1 = ppyr + (size_t)b * PYR_PER_IMG + offs[lvl];
        i2 = tpyr + (size_t)b * PYR_PER_IMG + offs[lvl];
    }

    int p = pblk * 256 + threadIdx.x;
    int y = p / w, x = p % w;

    // Gaussian window (double-normalized then cast, matching np) — constant-folds
    double gd[5]; double gs = 0.0;
    #pragma unroll
    for (int i = 0; i < 5; ++i) { gd[i] = exp(-(double)((i-2)*(i-2)) / 4.5); gs += gd[i]; }
    #pragma unroll
    for (int i = 0; i < 5; ++i) gd[i] /= gs;

    float m1 = 0.f, m2 = 0.f, m11 = 0.f, m22 = 0.f, m12 = 0.f;
    #pragma unroll
    for (int dy = -2; dy <= 2; ++dy) {
        int yy = y + dy;
        if ((unsigned)yy >= (unsigned)w) continue;
        #pragma unroll
        for (int dx = -2; dx <= 2; ++dx) {
            int xx = x + dx;
            if ((unsigned)xx >= (unsigned)w) continue;
            float wgt = (float)(gd[dy+2] * gd[dx+2]);
            float a = i1[yy * w + xx];
            float c = i2[yy * w + xx];
            m1  += wgt * a;
            m2  += wgt * c;
            m11 += wgt * a * a;
            m22 += wgt * c * c;
            m12 += wgt * a * c;
        }
    }
    const float C1 = (float)(0.01 * 0.01);
    const float C2 = (float)(0.03 * 0.03);
    float s1  = m11 - m1 * m1;
    float s2  = m22 - m2 * m2;
    float s12 = m12 - m1 * m2;
    float den2 = s1 + s2 + C2;
    float ssimv = ((2.0f*m1*m2 + C1) * (2.0f*s12 + C2)) / ((m1*m1 + m2*m2 + C1) * den2);
    float csv   = (2.0f*s12 + C2) / den2;

    float ssum = blockReduceSum(ssimv, red4);
    float csum = blockReduceSum(csv, red4);
    if (threadIdx.x == 0) {
        atomicAdd(&sAcc[b * 5 + lvl], (double)ssum);
        atomicAdd(&cAcc[b * 5 + lvl], (double)csum);
    }
}

__global__ void final_kernel(const unsigned* __restrict__ histP,
                             const unsigned* __restrict__ histT,
                             const double* __restrict__ sAcc,
                             const double* __restrict__ cAcc,
                             const double* __restrict__ labSum,
                             float* __restrict__ out) {
    __shared__ float red4[4];
    __shared__ float l1s[B];
    int t = threadIdx.x;
    for (int b = 0; b < B; ++b) {
        float s = 0.0f;
        for (int i = t; i < 3 * NBINS; i += 256) {
            int d = (int)histP[b * 3 * NBINS + i] - (int)histT[b * 3 * NBINS + i];
            s += fabsf((float)d);
        }
        float tot = blockReduceSum(s, red4);
        if (t == 0) l1s[b] = tot;
        __syncthreads();
    }
    if (t == 0) {
        float hist_loss = 0.0f;
        for (int b = 0; b < B; ++b) {
            float l1 = l1s[b] / (float)(3 * NBINS);
            float wgt = exp2f((float)(b - B));   // 2^(b - n), n = B = 8
            hist_loss += wgt * (l1 + 1.0f);
        }
        float scaler = (float)HW / 20.0f;
        hist_loss = hist_loss / (float)B / scaler;
        float lab_l1 = (float)(labSum[0] / (double)((size_t)B * 3 * HW));
        out[0] = lab_l1 + hist_loss;

        const float msw[5] = {0.0448f, 0.2856f, 0.3001f, 0.2363f, 0.1333f};
        const int npix[5] = {HW, HW/4, HW/16, HW/64, HW/256};
        float loss = 0.0f;
        for (int b = 0; b < B; ++b) {
            float ms = 1.0f;
            for (int l = 0; l < 4; ++l) {
                float cs = (float)(cAcc[b * 5 + l] / (double)npix[l]);
                float csn = (cs + 1.0f) / 2.0f;
                ms *= powf(csn, msw[l]);
            }
            float sm = (float)(sAcc[b * 5 + 4] / (double)npix[4]);
            float smn = (sm + 1.0f) / 2.0f;
            ms *= powf(smn, msw[4]);
            loss += 1.0f - ms;
        }
        out[1] = loss / (float)B;
    }
}

extern "C" void kernel_launch(void* const* d_in, const int* in_sizes, int n_in,
                              void* d_out, int out_size, void* d_ws, size_t ws_size,
                              hipStream_t stream) {
    const float* pred = (const float*)d_in[1];
    const float* tgt  = (const float*)d_in[2];
    float* ws_f = (float*)d_ws;

    float* predL = ws_f + OFF_PREDL;
    float* tgtL  = ws_f + OFF_TGTL;
    float* ppyr  = ws_f + OFF_PPYR;
    float* tpyr  = ws_f + OFF_TPYR;
    unsigned* histP = (unsigned*)(ws_f + OFF_HISTP);
    unsigned* histT = (unsigned*)(ws_f + OFF_HISTT);
    double* accs  = (double*)(ws_f + OFF_ACC);
    double* sAcc  = accs;        // B*5
    double* cAcc  = accs + B*5;  // B*5
    double* labSum = accs + 2*B*5;
    float* out = (float*)d_out;

    int zeroWords = 2 * B * 3 * NBINS + 81 * 2;
    zero_kernel<<<(zeroWords + 255)/256, 256, 0, stream>>>((unsigned*)(ws_f + OFF_HISTP), zeroWords);

    lab_hist_kernel<<<dim3(HW/1024, B), 256, 0, stream>>>(pred, tgt, ws_f, histP, histT, labSum);

    pyramid_kernel<<<dim3(256, B), 256, 0, stream>>>(predL, tgtL, ppyr, tpyr);

    ssim_kernel<<<dim3(1364, B), 256, 0, stream>>>(predL, tgtL, ppyr, tpyr, sAcc, cAcc);

    final_kernel<<<1, 256, 0, stream>>>(histP, histT, sAcc, cAcc, labSum, out);
}

// Round 3
// 195.004 us; speedup vs baseline: 1.9738x; 1.3574x over previous
//
#include <hip/hip_runtime.h>
#include <math.h>

#define B 8
#define IMH 512
#define IMW 512
#define HW (IMH*IMW)
#define NBINS 256

// pyramid per-image: levels 1..4 (256^2, 128^2, 64^2, 32^2)
#define PYR_PER_IMG (65536 + 16384 + 4096 + 1024)   // 87040
#define PYR_OFF_L1 0
#define PYR_OFF_L2 65536
#define PYR_OFF_L3 81920
#define PYR_OFF_L4 86016

// workspace float-index offsets
#define OFF_PREDL 0
#define OFF_TGTL  (B*HW)
#define OFF_PPYR  (2*B*HW)
#define OFF_TPYR  (OFF_PPYR + B*PYR_PER_IMG)
#define OFF_HISTP (OFF_TPYR + B*PYR_PER_IMG)        // uint32 region
#define OFF_HISTT (OFF_HISTP + B*3*NBINS)
#define OFF_ACC   (OFF_HISTT + B*3*NBINS)           // doubles (byte off divisible by 8)
// doubles: ssim_acc[B*5], cs_acc[B*5], lab_sum[1]  -> 81 doubles

__device__ __forceinline__ float blockReduceSum(float v, float* smem4) {
    int lane = threadIdx.x & 63;
    int wid  = threadIdx.x >> 6;
    #pragma unroll
    for (int o = 32; o >= 1; o >>= 1) v += __shfl_down(v, o, 64);
    if (lane == 0) smem4[wid] = v;
    __syncthreads();
    if (wid == 0) {
        v = (lane < ((int)blockDim.x >> 6)) ? smem4[lane] : 0.0f;
        #pragma unroll
        for (int o = 2; o >= 1; o >>= 1) v += __shfl_down(v, o, 64);
    }
    __syncthreads();   // allow smem4 reuse by a subsequent call
    return v;          // valid in thread 0
}

// native exp2/log2 (v_exp_f32 / v_log_f32, <=1 ulp). x must be > 0.
__device__ __forceinline__ float fastpow(float x, float y) {
    return __builtin_amdgcn_exp2f(y * __builtin_amdgcn_logf(x));
}

__device__ __forceinline__ void rgb2lab(float r, float g, float b, float* out) {
    float v[3] = {r, g, b};
    float lin[3];
    #pragma unroll
    for (int c = 0; c < 3; ++c) {
        float x = v[c];
        lin[c] = (x <= 0.04045f) ? (x * (float)(1.0/12.92))
                                 : fastpow((fmaxf(x, 1e-4f) + 0.055f) * (float)(1.0/1.055), 2.4f);
    }
    float X = 0.412453f*lin[0] + 0.357580f*lin[1] + 0.180423f*lin[2];
    float Y = 0.212671f*lin[0] + 0.715160f*lin[1] + 0.072169f*lin[2];
    float Z = 0.019334f*lin[0] + 0.119193f*lin[1] + 0.950227f*lin[2];
    X *= (float)(1.0/0.950456);
    Z *= (float)(1.0/1.088754);
    const float eps3   = (float)((6.0/29.0)*(6.0/29.0)*(6.0/29.0));
    const float rd3e2  = (float)(1.0/(3.0*(6.0/29.0)*(6.0/29.0)));
    const float c429   = (float)(4.0/29.0);
    float xyz[3] = {X, Y, Z};
    float f[3];
    #pragma unroll
    for (int c = 0; c < 3; ++c) {
        f[c] = (xyz[c] <= eps3) ? (xyz[c] * rd3e2 + c429)
                                : fastpow(fmaxf(xyz[c], 1e-4f), (float)(1.0/3.0));
    }
    float L = 116.0f*f[1] - 16.0f;
    float A = 500.0f*f[0] - 500.0f*f[1];
    float Bc = 200.0f*f[1] - 200.0f*f[2];
    out[0] = L * 0.01f;
    out[1] = (A * (float)(1.0/110.0) + 1.0f) * 0.5f;
    out[2] = (Bc * (float)(1.0/110.0) + 1.0f) * 0.5f;
}

__global__ void zero_kernel(unsigned* p, int n) {
    int i = blockIdx.x * 256 + threadIdx.x;
    if (i < n) p[i] = 0;
}

// 4 pixels per thread, float4 loads. grid (HW/1024, B) x 256
__global__ void lab_hist_kernel(const float* __restrict__ pred,
                                const float* __restrict__ tgt,
                                float* __restrict__ ws_f,
                                unsigned* __restrict__ histP,
                                unsigned* __restrict__ histT,
                                double* __restrict__ labSum) {
    __shared__ unsigned lhist[6 * NBINS];
    __shared__ float red4[4];
    int t = threadIdx.x;
    for (int i = t; i < 6 * NBINS; i += 256) lhist[i] = 0;
    __syncthreads();

    int b = blockIdx.y;
    int pix = (blockIdx.x * 256 + t) * 4;
    const float* pbase = pred + (size_t)b * 3 * HW + pix;
    const float* tbase = tgt  + (size_t)b * 3 * HW + pix;

    float4 pr = *(const float4*)(pbase);
    float4 pg = *(const float4*)(pbase + HW);
    float4 pb = *(const float4*)(pbase + 2*HW);
    float4 tr = *(const float4*)(tbase);
    float4 tg = *(const float4*)(tbase + HW);
    float4 tb = *(const float4*)(tbase + 2*HW);

    float prA[4] = {pr.x, pr.y, pr.z, pr.w};
    float pgA[4] = {pg.x, pg.y, pg.z, pg.w};
    float pbA[4] = {pb.x, pb.y, pb.z, pb.w};
    float trA[4] = {tr.x, tr.y, tr.z, tr.w};
    float tgA[4] = {tg.x, tg.y, tg.z, tg.w};
    float tbA[4] = {tb.x, tb.y, tb.z, tb.w};

    float l1 = 0.0f;
    float pls[4], tls[4];
    #pragma unroll
    for (int k = 0; k < 4; ++k) {
        float pl[3], tl[3];
        rgb2lab(prA[k], pgA[k], pbA[k], pl);
        rgb2lab(trA[k], tgA[k], tbA[k], tl);
        #pragma unroll
        for (int c = 0; c < 3; ++c) {
            pl[c] = fminf(fmaxf(pl[c], 0.0f), 1.0f);
            tl[c] = fminf(fmaxf(tl[c], 0.0f), 1.0f);
            l1 += fabsf(pl[c] - tl[c]);
            int ip = min(max((int)floorf(pl[c] * (float)NBINS), 0), NBINS - 1);
            int it = min(max((int)floorf(tl[c] * (float)NBINS), 0), NBINS - 1);
            atomicAdd(&lhist[c * NBINS + ip], 1u);
            atomicAdd(&lhist[(3 + c) * NBINS + it], 1u);
        }
        pls[k] = pl[0];
        tls[k] = tl[0];
    }

    // store clipped L channels for SSIM
    *(float4*)(ws_f + OFF_PREDL + (size_t)b * HW + pix) = make_float4(pls[0], pls[1], pls[2], pls[3]);
    *(float4*)(ws_f + OFF_TGTL  + (size_t)b * HW + pix) = make_float4(tls[0], tls[1], tls[2], tls[3]);

    __syncthreads();
    for (int i = t; i < 3 * NBINS; i += 256) {
        unsigned v = lhist[i];
        if (v) atomicAdd(&histP[b * 3 * NBINS + i], v);
        v = lhist[3 * NBINS + i];
        if (v) atomicAdd(&histT[b * 3 * NBINS + i], v);
    }

    float tot = blockReduceSum(l1, red4);
    if (t == 0) atomicAdd(labSum, (double)tot);
}

// one block = one 32x32 L0 tile -> produces L1 16x16, L2 8x8, L3 4x4, L4 2x2
// grid (256, B) x 256
__global__ void pyramid_kernel(const float* __restrict__ l0p,
                               const float* __restrict__ l0t,
                               float* __restrict__ ppyr,
                               float* __restrict__ tpyr) {
    __shared__ float s1[256];
    __shared__ float s2[64];
    __shared__ float s3[16];
    int b = blockIdx.y;
    int r = blockIdx.x;
    int ty0 = (r >> 4) << 5;
    int tx0 = (r & 15) << 5;
    int t = threadIdx.x;
    int ly = t >> 4, lx = t & 15;
    #pragma unroll
    for (int img = 0; img < 2; ++img) {
        const float* src = (img == 0 ? l0p : l0t) + (size_t)b * HW;
        float* dst = (img == 0 ? ppyr : tpyr) + (size_t)b * PYR_PER_IMG;
        int sy = ty0 + 2*ly, sx = tx0 + 2*lx;
        const float* s = src + sy * 512 + sx;
        float v1 = 0.25f * (s[0] + s[1] + s[512] + s[513]);
        dst[PYR_OFF_L1 + ((ty0 >> 1) + ly) * 256 + ((tx0 >> 1) + lx)] = v1;
        s1[t] = v1;
        __syncthreads();
        if (t < 64) {
            int y2 = t >> 3, x2 = t & 7;
            float v2 = 0.25f * (s1[(2*y2)*16 + 2*x2] + s1[(2*y2)*16 + 2*x2 + 1] +
                                s1[(2*y2+1)*16 + 2*x2] + s1[(2*y2+1)*16 + 2*x2 + 1]);
            dst[PYR_OFF_L2 + ((ty0 >> 2) + y2) * 128 + ((tx0 >> 2) + x2)] = v2;
            s2[t] = v2;
        }
        __syncthreads();
        if (t < 16) {
            int y3 = t >> 2, x3 = t & 3;
            float v3 = 0.25f * (s2[(2*y3)*8 + 2*x3] + s2[(2*y3)*8 + 2*x3 + 1] +
                                s2[(2*y3+1)*8 + 2*x3] + s2[(2*y3+1)*8 + 2*x3 + 1]);
            dst[PYR_OFF_L3 + ((ty0 >> 3) + y3) * 64 + ((tx0 >> 3) + x3)] = v3;
            s3[t] = v3;
        }
        __syncthreads();
        if (t < 4) {
            int y4 = t >> 1, x4 = t & 1;
            float v4 = 0.25f * (s3[(2*y4)*4 + 2*x4] + s3[(2*y4)*4 + 2*x4 + 1] +
                                s3[(2*y4+1)*4 + 2*x4] + s3[(2*y4+1)*4 + 2*x4 + 1]);
            dst[PYR_OFF_L4 + ((ty0 >> 4) + y4) * 32 + ((tx0 >> 4) + x4)] = v4;
        }
        __syncthreads();
    }
}

// LDS-tiled separable-conv SSIM, all 5 levels fused.
// one block = one 32x32 output tile; 341 blocks per image:
//   lvl0: 256 tiles, lvl1: 64, lvl2: 16, lvl3: 4, lvl4: 1
#define TILE 32
#define HALO 2
#define TS (TILE + 2*HALO)     // 36
#define TST 37                 // LDS row stride (odd -> 2-way max aliasing, free)
__global__ void ssim_kernel(const float* __restrict__ predL,
                            const float* __restrict__ tgtL,
                            const float* __restrict__ ppyr,
                            const float* __restrict__ tpyr,
                            double* __restrict__ sAcc,
                            double* __restrict__ cAcc) {
    __shared__ float t1s[TS * TST];
    __shared__ float t2s[TS * TST];
    __shared__ float red4[4];

    int b = blockIdx.y;
    int bx = blockIdx.x;
    int t = threadIdx.x;

    int lvl, pblk;
    if (bx < 256)      { lvl = 0; pblk = bx; }
    else if (bx < 320) { lvl = 1; pblk = bx - 256; }
    else if (bx < 336) { lvl = 2; pblk = bx - 320; }
    else if (bx < 340) { lvl = 3; pblk = bx - 336; }
    else               { lvl = 4; pblk = bx - 340; }

    const int offs[5] = {0, PYR_OFF_L1, PYR_OFF_L2, PYR_OFF_L3, PYR_OFF_L4};
    int w = 512 >> lvl;
    const float* i1;
    const float* i2;
    if (lvl == 0) {
        i1 = predL + (size_t)b * HW;
        i2 = tgtL  + (size_t)b * HW;
    } else {
        i1 = ppyr + (size_t)b * PYR_PER_IMG + offs[lvl];
        i2 = tpyr + (size_t)b * PYR_PER_IMG + offs[lvl];
    }

    int tprShift = 4 - lvl;                    // tiles per row = w/32 = 1<<tprShift
    int ty0 = (pblk >> tprShift) << 5;
    int tx0 = (pblk & ((1 << tprShift) - 1)) << 5;

    // stage 36x36 halo tiles (zero-padded at image edges)
    for (int i = t; i < TS * TS; i += 256) {
        int r = i / TS, c = i % TS;
        int gy = ty0 - HALO + r;
        int gx = tx0 - HALO + c;
        bool ok = ((unsigned)gy < (unsigned)w) && ((unsigned)gx < (unsigned)w);
        int gi = gy * w + gx;
        t1s[r * TST + c] = ok ? i1[gi] : 0.0f;
        t2s[r * TST + c] = ok ? i2[gi] : 0.0f;
    }
    __syncthreads();

    // Gaussian weights (double-normalized then cast, matches np; constant-folds)
    double gd[5]; double gs = 0.0;
    #pragma unroll
    for (int i = 0; i < 5; ++i) { gd[i] = exp(-(double)((i-2)*(i-2)) / 4.5); gs += gd[i]; }
    float gw[5];
    #pragma unroll
    for (int i = 0; i < 5; ++i) gw[i] = (float)(gd[i] / gs);

    int lx = t & 31;          // output column within tile
    int yg = t >> 5;          // row group: rows yg*4 .. yg*4+3

    // x-pass: row conv of the 5 fields for the 8 input rows this thread needs
    float r1[8], r2[8], r11[8], r22[8], r12[8];
    #pragma unroll
    for (int k = 0; k < 8; ++k) {
        int row = yg * 4 + k;                  // LDS row index (gy = ty0 + row - 2)
        const float* p1 = &t1s[row * TST + lx];
        const float* p2 = &t2s[row * TST + lx];
        float a1 = 0.f, a2 = 0.f, a11 = 0.f, a22 = 0.f, a12 = 0.f;
        #pragma unroll
        for (int dx = 0; dx < 5; ++dx) {
            float wv = gw[dx];
            float a = p1[dx];
            float c = p2[dx];
            a1  += wv * a;
            a2  += wv * c;
            a11 += wv * a * a;
            a22 += wv * c * c;
            a12 += wv * a * c;
        }
        r1[k] = a1; r2[k] = a2; r11[k] = a11; r22[k] = a22; r12[k] = a12;
    }

    // y-pass + ssim for 4 output pixels
    const float C1 = (float)(0.01 * 0.01);
    const float C2 = (float)(0.03 * 0.03);
    float ssum = 0.f, csum = 0.f;
    #pragma unroll
    for (int j = 0; j < 4; ++j) {
        float m1 = 0.f, m2 = 0.f, m11 = 0.f, m22 = 0.f, m12 = 0.f;
        #pragma unroll
        for (int k = 0; k < 5; ++k) {
            float wv = gw[k];
            m1  += wv * r1[j + k];
            m2  += wv * r2[j + k];
            m11 += wv * r11[j + k];
            m22 += wv * r22[j + k];
            m12 += wv * r12[j + k];
        }
        float s1  = m11 - m1 * m1;
        float s2  = m22 - m2 * m2;
        float s12 = m12 - m1 * m2;
        float den2 = s1 + s2 + C2;
        ssum += ((2.0f*m1*m2 + C1) * (2.0f*s12 + C2)) / ((m1*m1 + m2*m2 + C1) * den2);
        csum += (2.0f*s12 + C2) / den2;
    }

    float stot = blockReduceSum(ssum, red4);
    float ctot = blockReduceSum(csum, red4);
    if (t == 0) {
        atomicAdd(&sAcc[b * 5 + lvl], (double)stot);
        atomicAdd(&cAcc[b * 5 + lvl], (double)ctot);
    }
}

__global__ void final_kernel(const unsigned* __restrict__ histP,
                             const unsigned* __restrict__ histT,
                             const double* __restrict__ sAcc,
                             const double* __restrict__ cAcc,
                             const double* __restrict__ labSum,
                             float* __restrict__ out) {
    __shared__ float red4[4];
    __shared__ float l1s[B];
    int t = threadIdx.x;
    for (int b = 0; b < B; ++b) {
        float s = 0.0f;
        for (int i = t; i < 3 * NBINS; i += 256) {
            int d = (int)histP[b * 3 * NBINS + i] - (int)histT[b * 3 * NBINS + i];
            s += fabsf((float)d);
        }
        float tot = blockReduceSum(s, red4);
        if (t == 0) l1s[b] = tot;
        __syncthreads();
    }
    if (t == 0) {
        float hist_loss = 0.0f;
        for (int b = 0; b < B; ++b) {
            float l1 = l1s[b] / (float)(3 * NBINS);
            float wgt = exp2f((float)(b - B));   // 2^(b - n), n = B = 8
            hist_loss += wgt * (l1 + 1.0f);
        }
        float scaler = (float)HW / 20.0f;
        hist_loss = hist_loss / (float)B / scaler;
        float lab_l1 = (float)(labSum[0] / (double)((size_t)B * 3 * HW));
        out[0] = lab_l1 + hist_loss;

        const float msw[5] = {0.0448f, 0.2856f, 0.3001f, 0.2363f, 0.1333f};
        const int npix[5] = {HW, HW/4, HW/16, HW/64, HW/256};
        float loss = 0.0f;
        for (int b = 0; b < B; ++b) {
            float ms = 1.0f;
            for (int l = 0; l < 4; ++l) {
                float cs = (float)(cAcc[b * 5 + l] / (double)npix[l]);
                float csn = (cs + 1.0f) / 2.0f;
                ms *= powf(csn, msw[l]);
            }
            float sm = (float)(sAcc[b * 5 + 4] / (double)npix[4]);
            float smn = (sm + 1.0f) / 2.0f;
            ms *= powf(smn, msw[4]);
            loss += 1.0f - ms;
        }
        out[1] = loss / (float)B;
    }
}

extern "C" void kernel_launch(void* const* d_in, const int* in_sizes, int n_in,
                              void* d_out, int out_size, void* d_ws, size_t ws_size,
                              hipStream_t stream) {
    const float* pred = (const float*)d_in[1];
    const float* tgt  = (const float*)d_in[2];
    float* ws_f = (float*)d_ws;

    float* predL = ws_f + OFF_PREDL;
    float* tgtL  = ws_f + OFF_TGTL;
    float* ppyr  = ws_f + OFF_PPYR;
    float* tpyr  = ws_f + OFF_TPYR;
    unsigned* histP = (unsigned*)(ws_f + OFF_HISTP);
    unsigned* histT = (unsigned*)(ws_f + OFF_HISTT);
    double* accs  = (double*)(ws_f + OFF_ACC);
    double* sAcc  = accs;        // B*5
    double* cAcc  = accs + B*5;  // B*5
    double* labSum = accs + 2*B*5;
    float* out = (float*)d_out;

    int zeroWords = 2 * B * 3 * NBINS + 81 * 2;
    zero_kernel<<<(zeroWords + 255)/256, 256, 0, stream>>>((unsigned*)(ws_f + OFF_HISTP), zeroWords);

    lab_hist_kernel<<<dim3(HW/1024, B), 256, 0, stream>>>(pred, tgt, ws_f, histP, histT, labSum);

    pyramid_kernel<<<dim3(256, B), 256, 0, stream>>>(predL, tgtL, ppyr, tpyr);

    ssim_kernel<<<dim3(341, B), 256, 0, stream>>>(predL, tgtL, ppyr, tpyr, sAcc, cAcc);

    final_kernel<<<1, 256, 0, stream>>>(histP, histT, sAcc, cAcc, labSum, out);
}

// Round 4
// 177.785 us; speedup vs baseline: 2.1650x; 1.0969x over previous
//
#include <hip/hip_runtime.h>
#include <math.h>

#define B 8
#define IMH 512
#define IMW 512
#define HW (IMH*IMW)
#define NBINS 256

// pyramid per-image: levels 1..4 (256^2, 128^2, 64^2, 32^2)
#define PYR_PER_IMG (65536 + 16384 + 4096 + 1024)   // 87040
#define PYR_OFF_L1 0
#define PYR_OFF_L2 65536
#define PYR_OFF_L3 81920
#define PYR_OFF_L4 86016

// workspace float-index offsets
#define OFF_PREDL 0
#define OFF_TGTL  (B*HW)
#define OFF_PPYR  (2*B*HW)
#define OFF_TPYR  (OFF_PPYR + B*PYR_PER_IMG)
#define OFF_HISTP (OFF_TPYR + B*PYR_PER_IMG)        // uint32 region
#define OFF_HISTT (OFF_HISTP + B*3*NBINS)
#define OFF_ACC   (OFF_HISTT + B*3*NBINS)           // doubles (byte off divisible by 8)
// doubles: ssim_acc[B*5], cs_acc[B*5], lab_sum[1]  -> 81 doubles

__device__ __forceinline__ float blockReduceSum(float v, float* smem4) {
    int lane = threadIdx.x & 63;
    int wid  = threadIdx.x >> 6;
    #pragma unroll
    for (int o = 32; o >= 1; o >>= 1) v += __shfl_down(v, o, 64);
    if (lane == 0) smem4[wid] = v;
    __syncthreads();
    if (wid == 0) {
        v = (lane < ((int)blockDim.x >> 6)) ? smem4[lane] : 0.0f;
        #pragma unroll
        for (int o = 2; o >= 1; o >>= 1) v += __shfl_down(v, o, 64);
    }
    __syncthreads();   // allow smem4 reuse by a subsequent call
    return v;          // valid in thread 0
}

// native exp2/log2 (v_exp_f32 / v_log_f32, <=1 ulp). x must be > 0.
__device__ __forceinline__ float fastpow(float x, float y) {
    return __builtin_amdgcn_exp2f(y * __builtin_amdgcn_logf(x));
}

__device__ __forceinline__ void rgb2lab(float r, float g, float b, float* out) {
    float v[3] = {r, g, b};
    float lin[3];
    #pragma unroll
    for (int c = 0; c < 3; ++c) {
        float x = v[c];
        lin[c] = (x <= 0.04045f) ? (x * (float)(1.0/12.92))
                                 : fastpow((fmaxf(x, 1e-4f) + 0.055f) * (float)(1.0/1.055), 2.4f);
    }
    float X = 0.412453f*lin[0] + 0.357580f*lin[1] + 0.180423f*lin[2];
    float Y = 0.212671f*lin[0] + 0.715160f*lin[1] + 0.072169f*lin[2];
    float Z = 0.019334f*lin[0] + 0.119193f*lin[1] + 0.950227f*lin[2];
    X *= (float)(1.0/0.950456);
    Z *= (float)(1.0/1.088754);
    const float eps3   = (float)((6.0/29.0)*(6.0/29.0)*(6.0/29.0));
    const float rd3e2  = (float)(1.0/(3.0*(6.0/29.0)*(6.0/29.0)));
    const float c429   = (float)(4.0/29.0);
    float xyz[3] = {X, Y, Z};
    float f[3];
    #pragma unroll
    for (int c = 0; c < 3; ++c) {
        f[c] = (xyz[c] <= eps3) ? (xyz[c] * rd3e2 + c429)
                                : fastpow(fmaxf(xyz[c], 1e-4f), (float)(1.0/3.0));
    }
    float L = 116.0f*f[1] - 16.0f;
    float A = 500.0f*f[0] - 500.0f*f[1];
    float Bc = 200.0f*f[1] - 200.0f*f[2];
    out[0] = L * 0.01f;
    out[1] = (A * (float)(1.0/110.0) + 1.0f) * 0.5f;
    out[2] = (Bc * (float)(1.0/110.0) + 1.0f) * 0.5f;
}

__global__ void zero_kernel(unsigned* p, int n) {
    int i = blockIdx.x * 256 + threadIdx.x;
    if (i < n) p[i] = 0;
}

// Fused LAB + histogram + L-store + pyramid kernel.
// One block = 64x32 pixel region (two 32x32 pyramid base tiles side by side).
// grid (128, B) x 256; 8 px/thread in one row.
__global__ void lab_hist_pyr_kernel(const float* __restrict__ pred,
                                    const float* __restrict__ tgt,
                                    float* __restrict__ ws_f,
                                    unsigned* __restrict__ histP,
                                    unsigned* __restrict__ histT,
                                    double* __restrict__ labSum,
                                    float* __restrict__ ppyr,
                                    float* __restrict__ tpyr) {
    __shared__ float ls1[32 * 64];       // clipped L, pred
    __shared__ float ls2[32 * 64];       // clipped L, tgt
    __shared__ unsigned lhist[6 * NBINS];
    __shared__ float s1[2][16 * 32];     // L1 values for [pred, tgt]
    __shared__ float s2[2][8 * 16];
    __shared__ float s3[2][4 * 8];
    __shared__ float red4[4];

    int t = threadIdx.x;
    for (int i = t; i < 6 * NBINS; i += 256) lhist[i] = 0;
    __syncthreads();

    int b  = blockIdx.y;
    int bx = blockIdx.x;
    int tx0 = (bx & 7) << 6;     // region x origin (64-wide)
    int ty0 = (bx >> 3) << 5;    // region y origin (32-tall)
    int r  = t >> 3;             // row within region (0..31)
    int c8 = (t & 7) << 3;       // col within region (0,8,..,56)
    int gy = ty0 + r;

    size_t ibase = (size_t)b * 3 * HW + (size_t)gy * IMW + tx0 + c8;
    const float* pp = pred + ibase;
    const float* tp = tgt  + ibase;

    // 12 independent float4 loads issued up front (MLP)
    float prA[8], pgA[8], pbA[8], trA[8], tgA[8], tbA[8];
    *(float4*)&prA[0] = *(const float4*)(pp);          *(float4*)&prA[4] = *(const float4*)(pp + 4);
    *(float4*)&pgA[0] = *(const float4*)(pp + HW);     *(float4*)&pgA[4] = *(const float4*)(pp + HW + 4);
    *(float4*)&pbA[0] = *(const float4*)(pp + 2*HW);   *(float4*)&pbA[4] = *(const float4*)(pp + 2*HW + 4);
    *(float4*)&trA[0] = *(const float4*)(tp);          *(float4*)&trA[4] = *(const float4*)(tp + 4);
    *(float4*)&tgA[0] = *(const float4*)(tp + HW);     *(float4*)&tgA[4] = *(const float4*)(tp + HW + 4);
    *(float4*)&tbA[0] = *(const float4*)(tp + 2*HW);   *(float4*)&tbA[4] = *(const float4*)(tp + 2*HW + 4);

    float l1 = 0.0f;
    float pls[8], tls[8];
    #pragma unroll
    for (int k = 0; k < 8; ++k) {
        float pl[3], tl[3];
        rgb2lab(prA[k], pgA[k], pbA[k], pl);
        rgb2lab(trA[k], tgA[k], tbA[k], tl);
        #pragma unroll
        for (int c = 0; c < 3; ++c) {
            pl[c] = fminf(fmaxf(pl[c], 0.0f), 1.0f);
            tl[c] = fminf(fmaxf(tl[c], 0.0f), 1.0f);
            l1 += fabsf(pl[c] - tl[c]);
            int ip = min(max((int)floorf(pl[c] * (float)NBINS), 0), NBINS - 1);
            int it = min(max((int)floorf(tl[c] * (float)NBINS), 0), NBINS - 1);
            atomicAdd(&lhist[c * NBINS + ip], 1u);
            atomicAdd(&lhist[(3 + c) * NBINS + it], 1u);
        }
        pls[k] = pl[0];
        tls[k] = tl[0];
    }

    // store clipped L channels: global (for ssim lvl0) + LDS (for pyramid)
    size_t lbase = (size_t)b * HW + (size_t)gy * IMW + tx0 + c8;
    *(float4*)(ws_f + OFF_PREDL + lbase)     = *(float4*)&pls[0];
    *(float4*)(ws_f + OFF_PREDL + lbase + 4) = *(float4*)&pls[4];
    *(float4*)(ws_f + OFF_TGTL  + lbase)     = *(float4*)&tls[0];
    *(float4*)(ws_f + OFF_TGTL  + lbase + 4) = *(float4*)&tls[4];
    *(float4*)&ls1[r * 64 + c8]     = *(float4*)&pls[0];
    *(float4*)&ls1[r * 64 + c8 + 4] = *(float4*)&pls[4];
    *(float4*)&ls2[r * 64 + c8]     = *(float4*)&tls[0];
    *(float4*)&ls2[r * 64 + c8 + 4] = *(float4*)&tls[4];

    __syncthreads();

    // merge local histograms into global (overlaps with pyramid L1 below)
    for (int i = t; i < 3 * NBINS; i += 256) {
        unsigned v = lhist[i];
        if (v) atomicAdd(&histP[b * 3 * NBINS + i], v);
        v = lhist[3 * NBINS + i];
        if (v) atomicAdd(&histT[b * 3 * NBINS + i], v);
    }

    // pyramid L1: region -> 16x32 values per image (2 per thread per image)
    float* pyr[2] = {ppyr + (size_t)b * PYR_PER_IMG, tpyr + (size_t)b * PYR_PER_IMG};
    const float* lsrc[2] = {ls1, ls2};
    #pragma unroll
    for (int half = 0; half < 2; ++half) {
        int idx = t + half * 256;          // 0..511
        int y1 = idx >> 5, x1 = idx & 31;  // 16 x 32
        #pragma unroll
        for (int img = 0; img < 2; ++img) {
            const float* s = lsrc[img] + (2*y1) * 64 + 2*x1;
            float v = 0.25f * (s[0] + s[1] + s[64] + s[65]);
            s1[img][y1 * 32 + x1] = v;
            pyr[img][PYR_OFF_L1 + ((ty0 >> 1) + y1) * 256 + ((tx0 >> 1) + x1)] = v;
        }
    }
    __syncthreads();
    if (t < 128) {
        int y2 = t >> 4, x2 = t & 15;      // 8 x 16
        #pragma unroll
        for (int img = 0; img < 2; ++img) {
            const float* s = s1[img] + (2*y2) * 32 + 2*x2;
            float v = 0.25f * (s[0] + s[1] + s[32] + s[33]);
            s2[img][y2 * 16 + x2] = v;
            pyr[img][PYR_OFF_L2 + ((ty0 >> 2) + y2) * 128 + ((tx0 >> 2) + x2)] = v;
        }
    }
    __syncthreads();
    if (t < 32) {
        int y3 = t >> 3, x3 = t & 7;       // 4 x 8
        #pragma unroll
        for (int img = 0; img < 2; ++img) {
            const float* s = s2[img] + (2*y3) * 16 + 2*x3;
            float v = 0.25f * (s[0] + s[1] + s[16] + s[17]);
            s3[img][y3 * 8 + x3] = v;
            pyr[img][PYR_OFF_L3 + ((ty0 >> 3) + y3) * 64 + ((tx0 >> 3) + x3)] = v;
        }
    }
    __syncthreads();
    if (t < 8) {
        int y4 = t >> 2, x4 = t & 3;       // 2 x 4
        #pragma unroll
        for (int img = 0; img < 2; ++img) {
            const float* s = s3[img] + (2*y4) * 8 + 2*x4;
            float v = 0.25f * (s[0] + s[1] + s[8] + s[9]);
            pyr[img][PYR_OFF_L4 + ((ty0 >> 4) + y4) * 32 + ((tx0 >> 4) + x4)] = v;
        }
    }

    float tot = blockReduceSum(l1, red4);
    if (t == 0) atomicAdd(labSum, (double)tot);
}

// LDS-tiled separable-conv SSIM, all 5 levels fused.
// one block = one 32x32 output tile; 341 blocks per image:
//   lvl0: 256 tiles, lvl1: 64, lvl2: 16, lvl3: 4, lvl4: 1
#define TILE 32
#define HALO 2
#define TS (TILE + 2*HALO)     // 36
#define TST 37                 // LDS row stride (odd -> 2-way max aliasing, free)
__global__ void ssim_kernel(const float* __restrict__ predL,
                            const float* __restrict__ tgtL,
                            const float* __restrict__ ppyr,
                            const float* __restrict__ tpyr,
                            double* __restrict__ sAcc,
                            double* __restrict__ cAcc) {
    __shared__ float t1s[TS * TST];
    __shared__ float t2s[TS * TST];
    __shared__ float red4[4];

    int b = blockIdx.y;
    int bx = blockIdx.x;
    int t = threadIdx.x;

    int lvl, pblk;
    if (bx < 256)      { lvl = 0; pblk = bx; }
    else if (bx < 320) { lvl = 1; pblk = bx - 256; }
    else if (bx < 336) { lvl = 2; pblk = bx - 320; }
    else if (bx < 340) { lvl = 3; pblk = bx - 336; }
    else               { lvl = 4; pblk = bx - 340; }

    const int offs[5] = {0, PYR_OFF_L1, PYR_OFF_L2, PYR_OFF_L3, PYR_OFF_L4};
    int w = 512 >> lvl;
    const float* i1;
    const float* i2;
    if (lvl == 0) {
        i1 = predL + (size_t)b * HW;
        i2 = tgtL  + (size_t)b * HW;
    } else {
        i1 = ppyr + (size_t)b * PYR_PER_IMG + offs[lvl];
        i2 = tpyr + (size_t)b * PYR_PER_IMG + offs[lvl];
    }

    int tprShift = 4 - lvl;                    // tiles per row = w/32 = 1<<tprShift
    int ty0 = (pblk >> tprShift) << 5;
    int tx0 = (pblk & ((1 << tprShift) - 1)) << 5;

    // stage 36x36 halo tiles (zero-padded at image edges)
    for (int i = t; i < TS * TS; i += 256) {
        int r = i / TS, c = i % TS;
        int gy = ty0 - HALO + r;
        int gx = tx0 - HALO + c;
        bool ok = ((unsigned)gy < (unsigned)w) && ((unsigned)gx < (unsigned)w);
        int gi = gy * w + gx;
        t1s[r * TST + c] = ok ? i1[gi] : 0.0f;
        t2s[r * TST + c] = ok ? i2[gi] : 0.0f;
    }
    __syncthreads();

    // Gaussian weights (double-normalized then cast, matches np; constant-folds)
    double gd[5]; double gs = 0.0;
    #pragma unroll
    for (int i = 0; i < 5; ++i) { gd[i] = exp(-(double)((i-2)*(i-2)) / 4.5); gs += gd[i]; }
    float gw[5];
    #pragma unroll
    for (int i = 0; i < 5; ++i) gw[i] = (float)(gd[i] / gs);

    int lx = t & 31;          // output column within tile
    int yg = t >> 5;          // row group: rows yg*4 .. yg*4+3

    // x-pass: row conv of the 5 fields for the 8 input rows this thread needs
    float r1[8], r2[8], r11[8], r22[8], r12[8];
    #pragma unroll
    for (int k = 0; k < 8; ++k) {
        int row = yg * 4 + k;                  // LDS row index (gy = ty0 + row - 2)
        const float* p1 = &t1s[row * TST + lx];
        const float* p2 = &t2s[row * TST + lx];
        float a1 = 0.f, a2 = 0.f, a11 = 0.f, a22 = 0.f, a12 = 0.f;
        #pragma unroll
        for (int dx = 0; dx < 5; ++dx) {
            float wv = gw[dx];
            float a = p1[dx];
            float c = p2[dx];
            a1  += wv * a;
            a2  += wv * c;
            a11 += wv * a * a;
            a22 += wv * c * c;
            a12 += wv * a * c;
        }
        r1[k] = a1; r2[k] = a2; r11[k] = a11; r22[k] = a22; r12[k] = a12;
    }

    // y-pass + ssim for 4 output pixels
    const float C1 = (float)(0.01 * 0.01);
    const float C2 = (float)(0.03 * 0.03);
    float ssum = 0.f, csum = 0.f;
    #pragma unroll
    for (int j = 0; j < 4; ++j) {
        float m1 = 0.f, m2 = 0.f, m11 = 0.f, m22 = 0.f, m12 = 0.f;
        #pragma unroll
        for (int k = 0; k < 5; ++k) {
            float wv = gw[k];
            m1  += wv * r1[j + k];
            m2  += wv * r2[j + k];
            m11 += wv * r11[j + k];
            m22 += wv * r22[j + k];
            m12 += wv * r12[j + k];
        }
        float s1  = m11 - m1 * m1;
        float s2  = m22 - m2 * m2;
        float s12 = m12 - m1 * m2;
        float den2 = s1 + s2 + C2;
        ssum += ((2.0f*m1*m2 + C1) * (2.0f*s12 + C2)) / ((m1*m1 + m2*m2 + C1) * den2);
        csum += (2.0f*s12 + C2) / den2;
    }

    float stot = blockReduceSum(ssum, red4);
    float ctot = blockReduceSum(csum, red4);
    if (t == 0) {
        atomicAdd(&sAcc[b * 5 + lvl], (double)stot);
        atomicAdd(&cAcc[b * 5 + lvl], (double)ctot);
    }
}

__global__ void final_kernel(const unsigned* __restrict__ histP,
                             const unsigned* __restrict__ histT,
                             const double* __restrict__ sAcc,
                             const double* __restrict__ cAcc,
                             const double* __restrict__ labSum,
                             float* __restrict__ out) {
    __shared__ float red4[4];
    __shared__ float l1s[B];
    int t = threadIdx.x;
    for (int b = 0; b < B; ++b) {
        float s = 0.0f;
        for (int i = t; i < 3 * NBINS; i += 256) {
            int d = (int)histP[b * 3 * NBINS + i] - (int)histT[b * 3 * NBINS + i];
            s += fabsf((float)d);
        }
        float tot = blockReduceSum(s, red4);
        if (t == 0) l1s[b] = tot;
        __syncthreads();
    }
    if (t == 0) {
        float hist_loss = 0.0f;
        for (int b = 0; b < B; ++b) {
            float l1 = l1s[b] / (float)(3 * NBINS);
            float wgt = exp2f((float)(b - B));   // 2^(b - n), n = B = 8
            hist_loss += wgt * (l1 + 1.0f);
        }
        float scaler = (float)HW / 20.0f;
        hist_loss = hist_loss / (float)B / scaler;
        float lab_l1 = (float)(labSum[0] / (double)((size_t)B * 3 * HW));
        out[0] = lab_l1 + hist_loss;

        const float msw[5] = {0.0448f, 0.2856f, 0.3001f, 0.2363f, 0.1333f};
        const int npix[5] = {HW, HW/4, HW/16, HW/64, HW/256};
        float loss = 0.0f;
        for (int b = 0; b < B; ++b) {
            float ms = 1.0f;
            for (int l = 0; l < 4; ++l) {
                float cs = (float)(cAcc[b * 5 + l] / (double)npix[l]);
                float csn = (cs + 1.0f) / 2.0f;
                ms *= powf(csn, msw[l]);
            }
            float sm = (float)(sAcc[b * 5 + 4] / (double)npix[4]);
            float smn = (sm + 1.0f) / 2.0f;
            ms *= powf(smn, msw[4]);
            loss += 1.0f - ms;
        }
        out[1] = loss / (float)B;
    }
}

extern "C" void kernel_launch(void* const* d_in, const int* in_sizes, int n_in,
                              void* d_out, int out_size, void* d_ws, size_t ws_size,
                              hipStream_t stream) {
    const float* pred = (const float*)d_in[1];
    const float* tgt  = (const float*)d_in[2];
    float* ws_f = (float*)d_ws;

    float* predL = ws_f + OFF_PREDL;
    float* tgtL  = ws_f + OFF_TGTL;
    float* ppyr  = ws_f + OFF_PPYR;
    float* tpyr  = ws_f + OFF_TPYR;
    unsigned* histP = (unsigned*)(ws_f + OFF_HISTP);
    unsigned* histT = (unsigned*)(ws_f + OFF_HISTT);
    double* accs  = (double*)(ws_f + OFF_ACC);
    double* sAcc  = accs;        // B*5
    double* cAcc  = accs + B*5;  // B*5
    double* labSum = accs + 2*B*5;
    float* out = (float*)d_out;

    int zeroWords = 2 * B * 3 * NBINS + 81 * 2;
    zero_kernel<<<(zeroWords + 255)/256, 256, 0, stream>>>((unsigned*)(ws_f + OFF_HISTP), zeroWords);

    lab_hist_pyr_kernel<<<dim3(128, B), 256, 0, stream>>>(pred, tgt, ws_f, histP, histT,
                                                          labSum, ppyr, tpyr);

    ssim_kernel<<<dim3(341, B), 256, 0, stream>>>(predL, tgtL, ppyr, tpyr, sAcc, cAcc);

    final_kernel<<<1, 256, 0, stream>>>(histP, histT, sAcc, cAcc, labSum, out);
}

// Round 5
// 171.329 us; speedup vs baseline: 2.2466x; 1.0377x over previous
//
#include <hip/hip_runtime.h>
#include <math.h>

#define B 8
#define IMH 512
#define IMW 512
#define HW (IMH*IMW)
#define NBINS 256

// pyramid per-image: levels 1..4 (256^2, 128^2, 64^2, 32^2)
#define PYR_PER_IMG (65536 + 16384 + 4096 + 1024)   // 87040
#define PYR_OFF_L1 0
#define PYR_OFF_L2 65536
#define PYR_OFF_L3 81920
#define PYR_OFF_L4 86016

// workspace float-index offsets
#define OFF_PREDL 0
#define OFF_TGTL  (B*HW)
#define OFF_PPYR  (2*B*HW)
#define OFF_TPYR  (OFF_PPYR + B*PYR_PER_IMG)
#define OFF_HISTPART (OFF_TPYR + B*PYR_PER_IMG)     // u32: B*256*1536
#define OFF_LABPART  (OFF_HISTPART + B*256*1536)    // float: 2048
#define OFF_ACC      (OFF_LABPART + 2048)           // doubles (byte off % 8 == 0)
// doubles: sAcc[40], cAcc[40], histL1acc[8], labSumD[1] = 89 (first 88 zeroed by lab blk0)

__device__ __forceinline__ float blockReduceSum(float v, float* smem4) {
    int lane = threadIdx.x & 63;
    int wid  = threadIdx.x >> 6;
    #pragma unroll
    for (int o = 32; o >= 1; o >>= 1) v += __shfl_down(v, o, 64);
    if (lane == 0) smem4[wid] = v;
    __syncthreads();
    if (wid == 0) {
        v = (lane < ((int)blockDim.x >> 6)) ? smem4[lane] : 0.0f;
        #pragma unroll
        for (int o = 2; o >= 1; o >>= 1) v += __shfl_down(v, o, 64);
    }
    __syncthreads();   // allow smem4 reuse by a subsequent call
    return v;          // valid in thread 0
}

// native exp2/log2 (v_exp_f32 / v_log_f32, <=1 ulp). x must be > 0.
__device__ __forceinline__ float fastpow(float x, float y) {
    return __builtin_amdgcn_exp2f(y * __builtin_amdgcn_logf(x));
}

__device__ __forceinline__ void rgb2lab(float r, float g, float b, float* out) {
    float v[3] = {r, g, b};
    float lin[3];
    #pragma unroll
    for (int c = 0; c < 3; ++c) {
        float x = v[c];
        lin[c] = (x <= 0.04045f) ? (x * (float)(1.0/12.92))
                                 : fastpow((fmaxf(x, 1e-4f) + 0.055f) * (float)(1.0/1.055), 2.4f);
    }
    float X = 0.412453f*lin[0] + 0.357580f*lin[1] + 0.180423f*lin[2];
    float Y = 0.212671f*lin[0] + 0.715160f*lin[1] + 0.072169f*lin[2];
    float Z = 0.019334f*lin[0] + 0.119193f*lin[1] + 0.950227f*lin[2];
    X *= (float)(1.0/0.950456);
    Z *= (float)(1.0/1.088754);
    const float eps3   = (float)((6.0/29.0)*(6.0/29.0)*(6.0/29.0));
    const float rd3e2  = (float)(1.0/(3.0*(6.0/29.0)*(6.0/29.0)));
    const float c429   = (float)(4.0/29.0);
    float xyz[3] = {X, Y, Z};
    float f[3];
    #pragma unroll
    for (int c = 0; c < 3; ++c) {
        f[c] = (xyz[c] <= eps3) ? (xyz[c] * rd3e2 + c429)
                                : fastpow(fmaxf(xyz[c], 1e-4f), (float)(1.0/3.0));
    }
    float L = 116.0f*f[1] - 16.0f;
    float A = 500.0f*f[0] - 500.0f*f[1];
    float Bc = 200.0f*f[1] - 200.0f*f[2];
    out[0] = L * 0.01f;
    out[1] = (A * (float)(1.0/110.0) + 1.0f) * 0.5f;
    out[2] = (Bc * (float)(1.0/110.0) + 1.0f) * 0.5f;
}

// Fused LAB + histogram-partial + L-store + pyramid kernel.
// One block = 32x32 pixel region (one pyramid base tile). grid (256, B) x 256; 4 px/thread.
__global__ void lab_hist_pyr_kernel(const float* __restrict__ pred,
                                    const float* __restrict__ tgt,
                                    float* __restrict__ ws_f,
                                    unsigned* __restrict__ histPart,
                                    float* __restrict__ labPart,
                                    double* __restrict__ accs,
                                    float* __restrict__ ppyr,
                                    float* __restrict__ tpyr) {
    __shared__ unsigned lhist[6 * NBINS];
    __shared__ float s1[2][16 * 16];
    __shared__ float s2[2][8 * 8];
    __shared__ float s3[2][4 * 4];
    __shared__ float red4[4];

    int t  = threadIdx.x;
    int b  = blockIdx.y;
    int bx = blockIdx.x;

    // zero the accumulator doubles (consumed only by later-ordered kernels)
    if (bx == 0 && b == 0 && t < 88) accs[t] = 0.0;

    for (int i = t; i < 6 * NBINS; i += 256) lhist[i] = 0;
    __syncthreads();

    int tx0 = (bx & 15) << 5;    // tile x origin
    int ty0 = (bx >> 4) << 5;    // tile y origin
    int r   = t >> 3;            // row within tile (0..31)
    int c4  = (t & 7) << 2;      // col within tile (0,4,..,28)
    int gy  = ty0 + r;
    int gx  = tx0 + c4;

    size_t ibase = (size_t)b * 3 * HW + (size_t)gy * IMW + gx;
    const float* pp = pred + ibase;
    const float* tp = tgt  + ibase;

    // 6 independent float4 loads issued up front
    float prA[4], pgA[4], pbA[4], trA[4], tgA[4], tbA[4];
    *(float4*)&prA[0] = *(const float4*)(pp);
    *(float4*)&pgA[0] = *(const float4*)(pp + HW);
    *(float4*)&pbA[0] = *(const float4*)(pp + 2*HW);
    *(float4*)&trA[0] = *(const float4*)(tp);
    *(float4*)&tgA[0] = *(const float4*)(tp + HW);
    *(float4*)&tbA[0] = *(const float4*)(tp + 2*HW);

    float l1 = 0.0f;
    float pls[4], tls[4];
    #pragma unroll
    for (int k = 0; k < 4; ++k) {
        float pl[3], tl[3];
        rgb2lab(prA[k], pgA[k], pbA[k], pl);
        rgb2lab(trA[k], tgA[k], tbA[k], tl);
        #pragma unroll
        for (int c = 0; c < 3; ++c) {
            pl[c] = fminf(fmaxf(pl[c], 0.0f), 1.0f);
            tl[c] = fminf(fmaxf(tl[c], 0.0f), 1.0f);
            l1 += fabsf(pl[c] - tl[c]);
            int ip = min(max((int)floorf(pl[c] * (float)NBINS), 0), NBINS - 1);
            int it = min(max((int)floorf(tl[c] * (float)NBINS), 0), NBINS - 1);
            atomicAdd(&lhist[c * NBINS + ip], 1u);
            atomicAdd(&lhist[(3 + c) * NBINS + it], 1u);
        }
        pls[k] = pl[0];
        tls[k] = tl[0];
    }

    // store clipped L channels to global (for ssim lvl0)
    size_t lbase = (size_t)b * HW + (size_t)gy * IMW + gx;
    *(float4*)(ws_f + OFF_PREDL + lbase) = *(float4*)&pls[0];
    *(float4*)(ws_f + OFF_TGTL  + lbase) = *(float4*)&tls[0];

    // pyramid L1 from registers: horizontal pair sums + row-pair via shuffle
    float* pyrP = ppyr + (size_t)b * PYR_PER_IMG;
    float* pyrT = tpyr + (size_t)b * PYR_PER_IMG;
    float ph0 = pls[0] + pls[1], ph1 = pls[2] + pls[3];
    float th0 = tls[0] + tls[1], th1 = tls[2] + tls[3];
    float ph0b = __shfl_down(ph0, 8, 64);
    float ph1b = __shfl_down(ph1, 8, 64);
    float th0b = __shfl_down(th0, 8, 64);
    float th1b = __shfl_down(th1, 8, 64);
    if ((t & 8) == 0) {                 // even row r
        int y1 = r >> 1;                // 0..15
        int x1 = (t & 7) << 1;          // 0..14 (even)
        float pv0 = 0.25f * (ph0 + ph0b), pv1 = 0.25f * (ph1 + ph1b);
        float tv0 = 0.25f * (th0 + th0b), tv1 = 0.25f * (th1 + th1b);
        s1[0][y1 * 16 + x1]     = pv0;
        s1[0][y1 * 16 + x1 + 1] = pv1;
        s1[1][y1 * 16 + x1]     = tv0;
        s1[1][y1 * 16 + x1 + 1] = tv1;
        int g1 = ((ty0 >> 1) + y1) * 256 + (tx0 >> 1) + x1;
        *(float2*)&pyrP[PYR_OFF_L1 + g1] = make_float2(pv0, pv1);
        *(float2*)&pyrT[PYR_OFF_L1 + g1] = make_float2(tv0, tv1);
    }
    __syncthreads();

    // non-atomic per-block histogram partial (coalesced)
    unsigned* hp = histPart + ((size_t)b * 256 + bx) * 1536;
    for (int i = t; i < 1536; i += 256) hp[i] = lhist[i];

    // L2: 8x8 per image
    if (t < 64) {
        int y2 = t >> 3, x2 = t & 7;
        #pragma unroll
        for (int img = 0; img < 2; ++img) {
            const float* s = s1[img] + (2*y2) * 16 + 2*x2;
            float v = 0.25f * (s[0] + s[1] + s[16] + s[17]);
            s2[img][y2 * 8 + x2] = v;
            (img == 0 ? pyrP : pyrT)[PYR_OFF_L2 + ((ty0 >> 2) + y2) * 128 + (tx0 >> 2) + x2] = v;
        }
    }
    __syncthreads();
    if (t < 16) {
        int y3 = t >> 2, x3 = t & 3;
        #pragma unroll
        for (int img = 0; img < 2; ++img) {
            const float* s = s2[img] + (2*y3) * 8 + 2*x3;
            float v = 0.25f * (s[0] + s[1] + s[8] + s[9]);
            s3[img][y3 * 4 + x3] = v;
            (img == 0 ? pyrP : pyrT)[PYR_OFF_L3 + ((ty0 >> 3) + y3) * 64 + (tx0 >> 3) + x3] = v;
        }
    }
    __syncthreads();
    if (t < 4) {
        int y4 = t >> 1, x4 = t & 1;
        #pragma unroll
        for (int img = 0; img < 2; ++img) {
            const float* s = s3[img] + (2*y4) * 4 + 2*x4;
            float v = 0.25f * (s[0] + s[1] + s[4] + s[5]);
            (img == 0 ? pyrP : pyrT)[PYR_OFF_L4 + ((ty0 >> 4) + y4) * 32 + (tx0 >> 4) + x4] = v;
        }
    }

    float tot = blockReduceSum(l1, red4);
    if (t == 0) labPart[b * 256 + bx] = tot;
}

// blocks 0..23: hist partial reduce -> histL1acc[b]; block 24: labPart reduce -> labSumD
__global__ void reduce_kernel(const unsigned* __restrict__ histPart,
                              const float* __restrict__ labPart,
                              double* __restrict__ accs) {
    __shared__ float red4[4];
    int t = threadIdx.x;
    double* histL1acc = accs + 80;
    double* labSumD   = accs + 88;
    if (blockIdx.x < 24) {
        int gtid = blockIdx.x * 256 + t;        // 0..6143
        int b = gtid / 768;
        int j = gtid - b * 768;
        const unsigned* p = histPart + (size_t)b * 256 * 1536;
        int sp = 0, st = 0;
        for (int blk = 0; blk < 256; ++blk) {
            sp += (int)p[(size_t)blk * 1536 + j];
            st += (int)p[(size_t)blk * 1536 + j + 768];
        }
        float d = fabsf((float)(sp - st));       // exact: counts < 2^24
        float tot = blockReduceSum(d, red4);
        if (t == 0) atomicAdd(&histL1acc[b], (double)tot);
    } else {
        float s = 0.0f;
        #pragma unroll
        for (int k = 0; k < 8; ++k) s += labPart[t + k * 256];
        float tot = blockReduceSum(s, red4);
        if (t == 0) labSumD[0] = (double)tot;
    }
}

// LDS-tiled separable-conv SSIM, all 5 levels fused.
// one block = one 32x32 output tile; 341 blocks per image.
#define TILE 32
#define HALO 2
#define TS (TILE + 2*HALO)     // 36
#define TST 37                 // LDS row stride (odd -> 2-way max aliasing, free)
__global__ void ssim_kernel(const float* __restrict__ predL,
                            const float* __restrict__ tgtL,
                            const float* __restrict__ ppyr,
                            const float* __restrict__ tpyr,
                            double* __restrict__ accs) {
    __shared__ float t1s[TS * TST];
    __shared__ float t2s[TS * TST];
    __shared__ float red4[4];

    double* sAcc = accs;
    double* cAcc = accs + 40;

    int b = blockIdx.y;
    int bx = blockIdx.x;
    int t = threadIdx.x;

    int lvl, pblk;
    if (bx < 256)      { lvl = 0; pblk = bx; }
    else if (bx < 320) { lvl = 1; pblk = bx - 256; }
    else if (bx < 336) { lvl = 2; pblk = bx - 320; }
    else if (bx < 340) { lvl = 3; pblk = bx - 336; }
    else               { lvl = 4; pblk = bx - 340; }

    const int offs[5] = {0, PYR_OFF_L1, PYR_OFF_L2, PYR_OFF_L3, PYR_OFF_L4};
    int w = 512 >> lvl;
    const float* i1;
    const float* i2;
    if (lvl == 0) {
        i1 = predL + (size_t)b * HW;
        i2 = tgtL  + (size_t)b * HW;
    } else {
        i1 = ppyr + (size_t)b * PYR_PER_IMG + offs[lvl];
        i2 = tpyr + (size_t)b * PYR_PER_IMG + offs[lvl];
    }

    int tprShift = 4 - lvl;                    // tiles per row = w/32 = 1<<tprShift
    int ty0 = (pblk >> tprShift) << 5;
    int tx0 = (pblk & ((1 << tprShift) - 1)) << 5;

    // stage 36x36 halo tiles (zero-padded at image edges)
    for (int i = t; i < TS * TS; i += 256) {
        int r = i / TS, c = i % TS;
        int gy = ty0 - HALO + r;
        int gx = tx0 - HALO + c;
        bool ok = ((unsigned)gy < (unsigned)w) && ((unsigned)gx < (unsigned)w);
        int gi = gy * w + gx;
        t1s[r * TST + c] = ok ? i1[gi] : 0.0f;
        t2s[r * TST + c] = ok ? i2[gi] : 0.0f;
    }
    __syncthreads();

    // Gaussian weights (double-normalized then cast, matches np; constant-folds)
    double gd[5]; double gs = 0.0;
    #pragma unroll
    for (int i = 0; i < 5; ++i) { gd[i] = exp(-(double)((i-2)*(i-2)) / 4.5); gs += gd[i]; }
    float gw[5];
    #pragma unroll
    for (int i = 0; i < 5; ++i) gw[i] = (float)(gd[i] / gs);

    int lx = t & 31;          // output column within tile
    int yg = t >> 5;          // row group: rows yg*4 .. yg*4+3

    // x-pass: row conv of the 5 fields for the 8 input rows this thread needs
    float r1[8], r2[8], r11[8], r22[8], r12[8];
    #pragma unroll
    for (int k = 0; k < 8; ++k) {
        int row = yg * 4 + k;
        const float* p1 = &t1s[row * TST + lx];
        const float* p2 = &t2s[row * TST + lx];
        float a1 = 0.f, a2 = 0.f, a11 = 0.f, a22 = 0.f, a12 = 0.f;
        #pragma unroll
        for (int dx = 0; dx < 5; ++dx) {
            float wv = gw[dx];
            float a = p1[dx];
            float c = p2[dx];
            a1  += wv * a;
            a2  += wv * c;
            a11 += wv * a * a;
            a22 += wv * c * c;
            a12 += wv * a * c;
        }
        r1[k] = a1; r2[k] = a2; r11[k] = a11; r22[k] = a22; r12[k] = a12;
    }

    // y-pass + ssim for 4 output pixels
    const float C1 = (float)(0.01 * 0.01);
    const float C2 = (float)(0.03 * 0.03);
    float ssum = 0.f, csum = 0.f;
    #pragma unroll
    for (int j = 0; j < 4; ++j) {
        float m1 = 0.f, m2 = 0.f, m11 = 0.f, m22 = 0.f, m12 = 0.f;
        #pragma unroll
        for (int k = 0; k < 5; ++k) {
            float wv = gw[k];
            m1  += wv * r1[j + k];
            m2  += wv * r2[j + k];
            m11 += wv * r11[j + k];
            m22 += wv * r22[j + k];
            m12 += wv * r12[j + k];
        }
        float s1  = m11 - m1 * m1;
        float s2  = m22 - m2 * m2;
        float s12 = m12 - m1 * m2;
        float den2 = s1 + s2 + C2;
        ssum += ((2.0f*m1*m2 + C1) * (2.0f*s12 + C2)) / ((m1*m1 + m2*m2 + C1) * den2);
        csum += (2.0f*s12 + C2) / den2;
    }

    float stot = blockReduceSum(ssum, red4);
    float ctot = blockReduceSum(csum, red4);
    if (t == 0) {
        atomicAdd(&sAcc[b * 5 + lvl], (double)stot);
        atomicAdd(&cAcc[b * 5 + lvl], (double)ctot);
    }
}

__global__ void final_kernel(const double* __restrict__ accs,
                             float* __restrict__ out) {
    if (threadIdx.x == 0) {
        const double* sAcc = accs;
        const double* cAcc = accs + 40;
        const double* histL1acc = accs + 80;
        double labSum = accs[88];

        float hist_loss = 0.0f;
        for (int b = 0; b < B; ++b) {
            float l1 = (float)(histL1acc[b] / (double)(3 * NBINS));
            float wgt = exp2f((float)(b - B));   // 2^(b - n), n = B = 8
            hist_loss += wgt * (l1 + 1.0f);
        }
        float scaler = (float)HW / 20.0f;
        hist_loss = hist_loss / (float)B / scaler;
        float lab_l1 = (float)(labSum / (double)((size_t)B * 3 * HW));
        out[0] = lab_l1 + hist_loss;

        const float msw[5] = {0.0448f, 0.2856f, 0.3001f, 0.2363f, 0.1333f};
        const int npix[5] = {HW, HW/4, HW/16, HW/64, HW/256};
        float loss = 0.0f;
        for (int b = 0; b < B; ++b) {
            float ms = 1.0f;
            for (int l = 0; l < 4; ++l) {
                float cs = (float)(cAcc[b * 5 + l] / (double)npix[l]);
                float csn = (cs + 1.0f) / 2.0f;
                ms *= powf(csn, msw[l]);
            }
            float sm = (float)(sAcc[b * 5 + 4] / (double)npix[4]);
            float smn = (sm + 1.0f) / 2.0f;
            ms *= powf(smn, msw[4]);
            loss += 1.0f - ms;
        }
        out[1] = loss / (float)B;
    }
}

extern "C" void kernel_launch(void* const* d_in, const int* in_sizes, int n_in,
                              void* d_out, int out_size, void* d_ws, size_t ws_size,
                              hipStream_t stream) {
    const float* pred = (const float*)d_in[1];
    const float* tgt  = (const float*)d_in[2];
    float* ws_f = (float*)d_ws;

    float* predL = ws_f + OFF_PREDL;
    float* tgtL  = ws_f + OFF_TGTL;
    float* ppyr  = ws_f + OFF_PPYR;
    float* tpyr  = ws_f + OFF_TPYR;
    unsigned* histPart = (unsigned*)(ws_f + OFF_HISTPART);
    float* labPart = ws_f + OFF_LABPART;
    double* accs = (double*)(ws_f + OFF_ACC);
    float* out = (float*)d_out;

    lab_hist_pyr_kernel<<<dim3(256, B), 256, 0, stream>>>(pred, tgt, ws_f, histPart, labPart,
                                                          accs, ppyr, tpyr);

    ssim_kernel<<<dim3(341, B), 256, 0, stream>>>(predL, tgtL, ppyr, tpyr, accs);

    reduce_kernel<<<25, 256, 0, stream>>>(histPart, labPart, accs);

    final_kernel<<<1, 64, 0, stream>>>(accs, out);
}